// Round 9
// baseline (383.943 us; speedup 1.0000x reference)
//
#include <hip/hip_runtime.h>

#define GRID_DIM 132
#define SLAB (GRID_DIM * GRID_DIM)   // 17424
#define NB 512                       // 8x8x8 bins, each 16^3 in int(t) space
#define CHUNK 2048                   // points per partition/hist block
#define KPT (CHUNK / 256)            // 8 points per thread
#define REG 20                       // staged region edge (max tap index 19)
#define REG2 (REG * REG)
#define REG3 (REG * REG * REG)       // 8000 floats = 32 KB
#define STRIPE 8192                  // entries per scan_l1 block (2^13)

__device__ __forceinline__ void bspline_w(float x, float w[4]) {
    float omx = 1.0f - x;
    w[0] = omx * omx * omx * (1.0f / 6.0f);
    w[1] = (3.0f * (x - 2.0f) * x * x + 4.0f) * (1.0f / 6.0f);
    w[2] = (-3.0f * omx * omx * (x + 1.0f) + 4.0f) * (1.0f / 6.0f);
    w[3] = x * x * x * (1.0f / 6.0f);
}

__device__ __forceinline__ void load_pt(const float* __restrict__ pts, int i,
                                        float& tx, float& ty, float& tz, bool& inb) {
    tx = pts[3 * i + 0] + 1.0f;   // ORIGIN = -(1+1e-8) == -1.0f in fp32, STEP = 1
    ty = pts[3 * i + 1] + 1.0f;
    tz = pts[3 * i + 2] + 1.0f;
    inb = (tx >= 1.0f) && (ty >= 1.0f) && (tz >= 1.0f) &&
          (tx < 130.0f) && (ty < 130.0f) && (tz < 130.0f);
    if (!inb) { tx = ty = tz = 1.0f; }
}

// 512-bin id, x-major (proven)
__device__ __forceinline__ int calc_bin(float tx, float ty, float tz) {
    int bx = min(7, ((int)tx - 1) >> 4);
    int by = min(7, ((int)ty - 1) >> 4);
    int bz = min(7, ((int)tz - 1) >> 4);
    return (bx << 6) | (by << 3) | bz;
}

// m204 bijective XCD swizzle over chunk ids (shared by partition & unscatter
// so adjacent chunks -- whose runs share 64B lines -- live on the same XCD).
__device__ __forceinline__ int chunk_swizzle(int bid, int nblk) {
    int q = nblk >> 3, r = nblk & 7;
    int xcd = bid & 7, pos = bid >> 3;
    return (xcd < r ? xcd * (q + 1) : r * (q + 1) + (xcd - r) * q) + pos;
}

// In-LDS exclusive scan of stripe totals (<=256). Barriers unconditional.
__device__ __forceinline__ void local_stripe_scan(
    const unsigned* __restrict__ stot, int nstripe,
    unsigned* soff, unsigned* sc)
{
    int t = threadIdx.x;
    if (t < 256) sc[t] = (t < nstripe) ? stot[t] : 0u;
    __syncthreads();
    for (int off = 1; off < 256; off <<= 1) {
        unsigned v = (t >= off && t < 256) ? sc[t - off] : 0u;
        __syncthreads();
        if (t < 256) sc[t] += v;
        __syncthreads();
    }
    if (t < 256) soff[t] = (t == 0) ? 0u : sc[t - 1];
    __syncthreads();
}

// Per-chunk 512-bin histogram -> bh[bin*nblk + blk] (bin-major). No global atomics.
__global__ __launch_bounds__(256) void hist512_kernel(
    const float* __restrict__ pts, int n, int nblk, unsigned* __restrict__ bh)
{
    __shared__ unsigned lh[NB];
    int tid = threadIdx.x, blk = blockIdx.x;
    int c0 = blk * CHUNK;
    for (int b = tid; b < NB; b += 256) lh[b] = 0u;
    __syncthreads();
#pragma unroll
    for (int k = 0; k < KPT; ++k) {
        int i = c0 + tid + k * 256;
        if (i < n) {
            float tx, ty, tz; bool inb;
            load_pt(pts, i, tx, ty, tz, inb);
            atomicAdd(&lh[calc_bin(tx, ty, tz)], 1u);
        }
    }
    __syncthreads();
    for (int b = tid; b < NB; b += 256) bh[b * nblk + blk] = lh[b];
}

// Stripe-local exclusive scan (8192 entries/block) + stripe totals.
__global__ __launch_bounds__(256) void scan_l1_kernel(
    const unsigned* __restrict__ bh, unsigned* __restrict__ seg,
    unsigned* __restrict__ stot, int TOT)
{
    __shared__ unsigned sc[256];
    int t = threadIdx.x;
    int base_idx = blockIdx.x * STRIPE + t * 32;
    unsigned local[32];
    unsigned s = 0;
#pragma unroll
    for (int j = 0; j < 32; ++j) {
        int idx = base_idx + j;
        unsigned v = (idx < TOT) ? bh[idx] : 0u;
        local[j] = v; s += v;
    }
    sc[t] = s;
    __syncthreads();
    for (int off = 1; off < 256; off <<= 1) {
        unsigned v = (t >= off) ? sc[t - off] : 0u;
        __syncthreads();
        sc[t] += v;
        __syncthreads();
    }
    unsigned run = (t == 0) ? 0u : sc[t - 1];
#pragma unroll
    for (int j = 0; j < 32; ++j) {
        int idx = base_idx + j;
        if (idx < TOT) seg[idx] = run;
        run += local[j];
    }
    if (t == 255) stot[blockIdx.x] = sc[255];
}

// Bufless partition (proven r8): LDS cursors seeded with deterministic global
// segment starts; one pass, direct writes into per-(chunk,bin) runs.
__global__ __launch_bounds__(256) void partition_kernel(
    const float* __restrict__ pts, int n, int nblk,
    const unsigned* __restrict__ seg, const unsigned* __restrict__ stot,
    int nstripe, float4* __restrict__ sorted, unsigned* __restrict__ inv)
{
    __shared__ unsigned lcur[NB];                 // 2 KB
    __shared__ unsigned sc[256], soff[256];       // 2 KB

    local_stripe_scan(stot, nstripe, soff, sc);

    int blk = chunk_swizzle(blockIdx.x, nblk);
    int tid = threadIdx.x;
    int c0 = blk * CHUNK;

    for (int b = tid; b < NB; b += 256) {
        int idx = b * nblk + blk;
        lcur[b] = seg[idx] + soff[idx >> 13];     // STRIPE = 2^13
    }
    __syncthreads();

#pragma unroll
    for (int k = 0; k < KPT; ++k) {
        int i = c0 + tid + k * 256;
        if (i < n) {
            float tx, ty, tz; bool inb;
            load_pt(pts, i, tx, ty, tz, inb);
            int bin = calc_bin(tx, ty, tz);
            unsigned g = atomicAdd(&lcur[bin], 1u);
            unsigned tag = (unsigned)i | (inb ? 0u : 0x80000000u);
            sorted[g] = make_float4(tx, ty, tz, __uint_as_float(tag));
            inv[i] = g;                           // dense, coalesced
        }
    }
}

// One 512-thread block per bin: stage the bin's 20^3 region in LDS ONCE,
// evaluate its points, write val_s dense by sorted position. (Proven r7/r8.)
__global__ __launch_bounds__(512) void eval_kernel(
    const float4* __restrict__ sorted, const float* __restrict__ cp,
    const unsigned* __restrict__ seg, const unsigned* __restrict__ stot,
    int nstripe, float* __restrict__ val_s, int n, int nblk)
{
    __shared__ float region[REG3];   // 32 KB
    __shared__ unsigned sc[256], soff[256];

    local_stripe_scan(stot, nstripe, soff, sc);

    int bid = blockIdx.x;
    int bin = (bid & 7) * 64 + (bid >> 3);   // 512 = 8 XCDs x 64 bins
    int x0 = (bin >> 6) << 4, y0 = ((bin >> 3) & 7) << 4, z0 = (bin & 7) << 4;

    const float* src = cp + (size_t)x0 * SLAB + y0 * GRID_DIM + z0;
    for (int v = threadIdx.x; v < REG3; v += 512) {
        int gx = v / REG2;
        int rr = v - gx * REG2;
        int gy = rr / REG;
        int gz = rr - gy * REG;
        region[v] = src[gx * SLAB + gy * GRID_DIM + gz];
    }
    __syncthreads();

    int i0 = bin * nblk;
    unsigned s = seg[i0] + soff[i0 >> 13];
    unsigned e;
    if (bin == NB - 1) e = (unsigned)n;
    else { int i1 = (bin + 1) * nblk; e = seg[i1] + soff[i1 >> 13]; }

    for (unsigned i = s + threadIdx.x; i < e; i += 512) {
        float4 p = sorted[i];
        unsigned tag = __float_as_uint(p.w);
        int ix = (int)p.x, iy = (int)p.y, iz = (int)p.z;
        float wx[4], wy[4], wz[4];
        bspline_w(p.x - (float)ix, wx);
        bspline_w(p.y - (float)iy, wy);
        bspline_w(p.z - (float)iz, wz);
        int lx = ix - 1 - x0, ly = iy - 1 - y0, lz = iz - 1 - z0;
        const float* rb = region + (lx * REG + ly) * REG + lz;
        float acc = 0.0f;
#pragma unroll
        for (int a = 0; a < 4; ++a) {
            float accy = 0.0f;
#pragma unroll
            for (int b = 0; b < 4; ++b) {
                const float* row = rb + (a * REG + b) * REG;
                float sz = fmaf(row[0], wz[0], fmaf(row[1], wz[1],
                           fmaf(row[2], wz[2], row[3] * wz[3])));
                accy = fmaf(wy[b], sz, accy);
            }
            acc = fmaf(wx[a], accy, acc);
        }
        val_s[i] = (tag >> 31) ? 0.0f : acc;
    }
}

// Run-structured unscatter: one block per chunk. Chunk c's 2048 values live in
// 512 CONTIGUOUS runs of val_s whose starts gseg[b] are monotone in b.
// Phase 1: gather runs into 8KB LDS lbuf (512 line-touches vs 2048 random).
// Phase 2: bin = binary-search(inv[i] in gseg), out[i] = lbuf[lrs[bin]+rank].
// Deterministic; dense coalesced inv reads and out writes.
__global__ __launch_bounds__(256) void unscatter_kernel(
    const float* __restrict__ val_s, const unsigned* __restrict__ inv,
    const unsigned* __restrict__ seg, const unsigned* __restrict__ stot,
    int nstripe, float* __restrict__ out, int n, int nblk)
{
    __shared__ unsigned sc[256], soff[256];       // 2 KB
    __shared__ unsigned gsegS[NB];                // 2 KB (monotone run starts)
    __shared__ unsigned lrs[NB];                  // 2 KB (local run starts)
    __shared__ float lbuf[CHUNK];                 // 8 KB

    local_stripe_scan(stot, nstripe, soff, sc);

    int blk = chunk_swizzle(blockIdx.x, nblk);    // same mapping as partition
    int tid = threadIdx.x;
    int c0 = blk * CHUNK;

    // this chunk's 512 run starts (global) + lengths
    unsigned len2[2];
#pragma unroll
    for (int j = 0; j < 2; ++j) {
        int b = 2 * tid + j;
        int idx = b * nblk + blk;
        unsigned st = seg[idx] + soff[idx >> 13];
        gsegS[b] = st;
        int idx1 = idx + 1;
        unsigned en = (idx1 < NB * nblk) ? (seg[idx1] + soff[idx1 >> 13])
                                         : (unsigned)n;
        len2[j] = en - st;
    }
    sc[tid] = len2[0] + len2[1];
    __syncthreads();                               // covers gsegS + sc
    for (int off = 1; off < 256; off <<= 1) {
        unsigned v = (tid >= off) ? sc[tid - off] : 0u;
        __syncthreads();
        sc[tid] += v;
        __syncthreads();
    }
    unsigned base = (tid == 0) ? 0u : sc[tid - 1];
    lrs[2 * tid] = base;
    lrs[2 * tid + 1] = base + len2[0];
    __syncthreads();

    // phase 1: gather this chunk's values (bin-major) into lbuf
#pragma unroll
    for (int j = 0; j < 2; ++j) {
        int b = 2 * tid + j;
        unsigned st = gsegS[b], l = len2[j], d = lrs[b];
        for (unsigned k = 0; k < l; ++k) lbuf[d + k] = val_s[st + k];
    }
    __syncthreads();

    // phase 2: dense writes via 9-step binary search in monotone gsegS
#pragma unroll
    for (int k = 0; k < KPT; ++k) {
        int i = c0 + tid + k * 256;
        if (i < n) {
            unsigned g = inv[i];
            unsigned lo = 0, hi = NB;
            while (hi - lo > 1) {
                unsigned mid = (lo + hi) >> 1;
                if (gsegS[mid] <= g) lo = mid; else hi = mid;
            }
            out[i] = lbuf[lrs[lo] + (g - gsegS[lo])];
        }
    }
}

// Fallback (round-1 proven) if ws/config insufficient.
__global__ __launch_bounds__(256) void eval_unsorted_kernel(
    const float* __restrict__ pts, const float* __restrict__ cp,
    float* __restrict__ out, int n)
{
    int i = blockIdx.x * blockDim.x + threadIdx.x;
    if (i >= n) return;
    float tx, ty, tz; bool inb;
    load_pt(pts, i, tx, ty, tz, inb);
    int ix = (int)tx, iy = (int)ty, iz = (int)tz;
    float wx[4], wy[4], wz[4];
    bspline_w(tx - (float)ix, wx);
    bspline_w(ty - (float)iy, wy);
    bspline_w(tz - (float)iz, wz);
    const float* bse = cp + (size_t)(ix - 1) * SLAB + (size_t)(iy - 1) * GRID_DIM + (iz - 1);
    float acc = 0.0f;
#pragma unroll
    for (int a = 0; a < 4; ++a) {
        float accy = 0.0f;
#pragma unroll
        for (int b = 0; b < 4; ++b) {
            const float* row = bse + a * SLAB + b * GRID_DIM;
            float4 v;
            __builtin_memcpy(&v, row, 16);
            float sz = fmaf(v.x, wz[0], fmaf(v.y, wz[1], fmaf(v.z, wz[2], v.w * wz[3])));
            accy = fmaf(wy[b], sz, accy);
        }
        acc = fmaf(wx[a], accy, acc);
    }
    out[i] = inb ? acc : 0.0f;
}

extern "C" void kernel_launch(void* const* d_in, const int* in_sizes, int n_in,
                              void* d_out, int out_size, void* d_ws, size_t ws_size,
                              hipStream_t stream) {
    const float* pts = (const float*)d_in[0];      // (N, 3) fp32
    const float* cp  = (const float*)d_in[1];      // (1, 132, 132, 132) fp32
    float* out       = (float*)d_out;              // (N, 1) fp32

    int n = in_sizes[0] / 3;                       // 2,000,000
    int nblk = (n + CHUNK - 1) / CHUNK;            // 977
    int TOT = NB * nblk;                           // 500,224
    int nstripe = (TOT + STRIPE - 1) / STRIPE;     // 62

    // ws layout (all fully rewritten every call; no memsets needed):
    // bh[TOT] | seg[TOT] | stot[256] | sorted f4[n] | inv u32[n] | val_s f32[n]
    size_t A          = (((size_t)TOT * 4) + 1023) & ~(size_t)1023;
    size_t off_seg    = A;
    size_t off_stot   = 2 * A;
    size_t off_sorted = 2 * A + 1024;
    size_t off_inv    = off_sorted + (size_t)n * sizeof(float4);
    size_t off_val    = off_inv    + (size_t)n * sizeof(unsigned);
    size_t need       = off_val    + (size_t)n * sizeof(float);

    if (ws_size >= need && nblk <= 1024 && nstripe <= 256 && n % CHUNK == 0) {
        unsigned* bh     = (unsigned*)d_ws;
        unsigned* seg    = (unsigned*)((char*)d_ws + off_seg);
        unsigned* stot   = (unsigned*)((char*)d_ws + off_stot);
        float4*   sorted = (float4*)((char*)d_ws + off_sorted);
        unsigned* inv    = (unsigned*)((char*)d_ws + off_inv);
        float*    val_s  = (float*)((char*)d_ws + off_val);

        hipLaunchKernelGGL(hist512_kernel, dim3(nblk), dim3(256), 0, stream,
                           pts, n, nblk, bh);
        hipLaunchKernelGGL(scan_l1_kernel, dim3(nstripe), dim3(256), 0, stream,
                           bh, seg, stot, TOT);
        hipLaunchKernelGGL(partition_kernel, dim3(nblk), dim3(256), 0, stream,
                           pts, n, nblk, seg, stot, nstripe, sorted, inv);
        hipLaunchKernelGGL(eval_kernel, dim3(NB), dim3(512), 0, stream,
                           sorted, cp, seg, stot, nstripe, val_s, n, nblk);
        hipLaunchKernelGGL(unscatter_kernel, dim3(nblk), dim3(256), 0, stream,
                           val_s, inv, seg, stot, nstripe, out, n, nblk);
    } else {
        hipLaunchKernelGGL(eval_unsorted_kernel, dim3((n + 255) / 256), dim3(256), 0, stream,
                           pts, cp, out, n);
    }
}

// Round 10
// 176.186 us; speedup vs baseline: 2.1792x; 2.1792x over previous
//
#include <hip/hip_runtime.h>

#define GRID_DIM 132
#define SLAB (GRID_DIM * GRID_DIM)   // 17424
#define NB 512                       // 8x8x8 bins, each 16^3 in int(t) space
#define CHUNK 2048                   // points per partition/hist block
#define KPT (CHUNK / 256)            // 8 points per thread
#define REG 20                       // staged region edge (max tap index 19)
#define REG2 (REG * REG)
#define REG3 (REG * REG * REG)       // 8000 floats = 32 KB
#define STRIPE 8192                  // entries per scan_l1 block (2^13)

__device__ __forceinline__ void bspline_w(float x, float w[4]) {
    float omx = 1.0f - x;
    w[0] = omx * omx * omx * (1.0f / 6.0f);
    w[1] = (3.0f * (x - 2.0f) * x * x + 4.0f) * (1.0f / 6.0f);
    w[2] = (-3.0f * omx * omx * (x + 1.0f) + 4.0f) * (1.0f / 6.0f);
    w[3] = x * x * x * (1.0f / 6.0f);
}

__device__ __forceinline__ void load_pt(const float* __restrict__ pts, int i,
                                        float& tx, float& ty, float& tz, bool& inb) {
    tx = pts[3 * i + 0] + 1.0f;   // ORIGIN = -(1+1e-8) == -1.0f in fp32, STEP = 1
    ty = pts[3 * i + 1] + 1.0f;
    tz = pts[3 * i + 2] + 1.0f;
    inb = (tx >= 1.0f) && (ty >= 1.0f) && (tz >= 1.0f) &&
          (tx < 130.0f) && (ty < 130.0f) && (tz < 130.0f);
    if (!inb) { tx = ty = tz = 1.0f; }
}

// 512-bin id, x-major (proven)
__device__ __forceinline__ int calc_bin(float tx, float ty, float tz) {
    int bx = min(7, ((int)tx - 1) >> 4);
    int by = min(7, ((int)ty - 1) >> 4);
    int bz = min(7, ((int)tz - 1) >> 4);
    return (bx << 6) | (by << 3) | bz;
}

// m204 bijective XCD swizzle over chunk ids (shared by partition & unscatter
// so adjacent chunks -- whose runs share 64B lines -- live on the same XCD).
__device__ __forceinline__ int chunk_swizzle(int bid, int nblk) {
    int q = nblk >> 3, r = nblk & 7;
    int xcd = bid & 7, pos = bid >> 3;
    return (xcd < r ? xcd * (q + 1) : r * (q + 1) + (xcd - r) * q) + pos;
}

// In-LDS exclusive scan of stripe totals (<=256). Barriers unconditional.
__device__ __forceinline__ void local_stripe_scan(
    const unsigned* __restrict__ stot, int nstripe,
    unsigned* soff, unsigned* sc)
{
    int t = threadIdx.x;
    if (t < 256) sc[t] = (t < nstripe) ? stot[t] : 0u;
    __syncthreads();
    for (int off = 1; off < 256; off <<= 1) {
        unsigned v = (t >= off && t < 256) ? sc[t - off] : 0u;
        __syncthreads();
        if (t < 256) sc[t] += v;
        __syncthreads();
    }
    if (t < 256) soff[t] = (t == 0) ? 0u : sc[t - 1];
    __syncthreads();
}

// Per-chunk 512-bin histogram -> bh[bin*nblk + blk] (bin-major). No global atomics.
__global__ __launch_bounds__(256) void hist512_kernel(
    const float* __restrict__ pts, int n, int nblk, unsigned* __restrict__ bh)
{
    __shared__ unsigned lh[NB];
    int tid = threadIdx.x, blk = blockIdx.x;
    int c0 = blk * CHUNK;
    for (int b = tid; b < NB; b += 256) lh[b] = 0u;
    __syncthreads();
#pragma unroll
    for (int k = 0; k < KPT; ++k) {
        int i = c0 + tid + k * 256;
        if (i < n) {
            float tx, ty, tz; bool inb;
            load_pt(pts, i, tx, ty, tz, inb);
            atomicAdd(&lh[calc_bin(tx, ty, tz)], 1u);
        }
    }
    __syncthreads();
    for (int b = tid; b < NB; b += 256) bh[b * nblk + blk] = lh[b];
}

// Stripe-local exclusive scan (8192 entries/block) + stripe totals.
__global__ __launch_bounds__(256) void scan_l1_kernel(
    const unsigned* __restrict__ bh, unsigned* __restrict__ seg,
    unsigned* __restrict__ stot, int TOT)
{
    __shared__ unsigned sc[256];
    int t = threadIdx.x;
    int base_idx = blockIdx.x * STRIPE + t * 32;
    unsigned local[32];
    unsigned s = 0;
#pragma unroll
    for (int j = 0; j < 32; ++j) {
        int idx = base_idx + j;
        unsigned v = (idx < TOT) ? bh[idx] : 0u;
        local[j] = v; s += v;
    }
    sc[t] = s;
    __syncthreads();
    for (int off = 1; off < 256; off <<= 1) {
        unsigned v = (t >= off) ? sc[t - off] : 0u;
        __syncthreads();
        sc[t] += v;
        __syncthreads();
    }
    unsigned run = (t == 0) ? 0u : sc[t - 1];
#pragma unroll
    for (int j = 0; j < 32; ++j) {
        int idx = base_idx + j;
        if (idx < TOT) seg[idx] = run;
        run += local[j];
    }
    if (t == 255) stot[blockIdx.x] = sc[255];
}

// Bufless partition (proven r8): LDS cursors seeded with deterministic global
// segment starts; one pass, direct writes into per-(chunk,bin) runs.
__global__ __launch_bounds__(256) void partition_kernel(
    const float* __restrict__ pts, int n, int nblk,
    const unsigned* __restrict__ seg, const unsigned* __restrict__ stot,
    int nstripe, float4* __restrict__ sorted, unsigned* __restrict__ inv)
{
    __shared__ unsigned lcur[NB];                 // 2 KB
    __shared__ unsigned sc[256], soff[256];       // 2 KB

    local_stripe_scan(stot, nstripe, soff, sc);

    int blk = chunk_swizzle(blockIdx.x, nblk);
    int tid = threadIdx.x;
    int c0 = blk * CHUNK;

    for (int b = tid; b < NB; b += 256) {
        int idx = b * nblk + blk;
        lcur[b] = seg[idx] + soff[idx >> 13];     // STRIPE = 2^13
    }
    __syncthreads();

#pragma unroll
    for (int k = 0; k < KPT; ++k) {
        int i = c0 + tid + k * 256;
        if (i < n) {
            float tx, ty, tz; bool inb;
            load_pt(pts, i, tx, ty, tz, inb);
            int bin = calc_bin(tx, ty, tz);
            unsigned g = atomicAdd(&lcur[bin], 1u);
            unsigned tag = (unsigned)i | (inb ? 0u : 0x80000000u);
            sorted[g] = make_float4(tx, ty, tz, __uint_as_float(tag));
            inv[i] = g;                           // dense, coalesced
        }
    }
}

// One 512-thread block per bin: stage the bin's 20^3 region in LDS ONCE,
// evaluate its points, write val_s dense by sorted position. (Proven r7/r8.)
__global__ __launch_bounds__(512) void eval_kernel(
    const float4* __restrict__ sorted, const float* __restrict__ cp,
    const unsigned* __restrict__ seg, const unsigned* __restrict__ stot,
    int nstripe, float* __restrict__ val_s, int n, int nblk)
{
    __shared__ float region[REG3];   // 32 KB
    __shared__ unsigned sc[256], soff[256];

    local_stripe_scan(stot, nstripe, soff, sc);

    int bid = blockIdx.x;
    int bin = (bid & 7) * 64 + (bid >> 3);   // 512 = 8 XCDs x 64 bins
    int x0 = (bin >> 6) << 4, y0 = ((bin >> 3) & 7) << 4, z0 = (bin & 7) << 4;

    const float* src = cp + (size_t)x0 * SLAB + y0 * GRID_DIM + z0;
    for (int v = threadIdx.x; v < REG3; v += 512) {
        int gx = v / REG2;
        int rr = v - gx * REG2;
        int gy = rr / REG;
        int gz = rr - gy * REG;
        region[v] = src[gx * SLAB + gy * GRID_DIM + gz];
    }
    __syncthreads();

    int i0 = bin * nblk;
    unsigned s = seg[i0] + soff[i0 >> 13];
    unsigned e;
    if (bin == NB - 1) e = (unsigned)n;
    else { int i1 = (bin + 1) * nblk; e = seg[i1] + soff[i1 >> 13]; }

    for (unsigned i = s + threadIdx.x; i < e; i += 512) {
        float4 p = sorted[i];
        unsigned tag = __float_as_uint(p.w);
        int ix = (int)p.x, iy = (int)p.y, iz = (int)p.z;
        float wx[4], wy[4], wz[4];
        bspline_w(p.x - (float)ix, wx);
        bspline_w(p.y - (float)iy, wy);
        bspline_w(p.z - (float)iz, wz);
        int lx = ix - 1 - x0, ly = iy - 1 - y0, lz = iz - 1 - z0;
        const float* rb = region + (lx * REG + ly) * REG + lz;
        float acc = 0.0f;
#pragma unroll
        for (int a = 0; a < 4; ++a) {
            float accy = 0.0f;
#pragma unroll
            for (int b = 0; b < 4; ++b) {
                const float* row = rb + (a * REG + b) * REG;
                float sz = fmaf(row[0], wz[0], fmaf(row[1], wz[1],
                           fmaf(row[2], wz[2], row[3] * wz[3])));
                accy = fmaf(wy[b], sz, accy);
            }
            acc = fmaf(wx[a], accy, acc);
        }
        val_s[i] = (tag >> 31) ? 0.0f : acc;
    }
}

// Run-structured unscatter: one block per chunk. Chunk c's values live in 512
// CONTIGUOUS runs of val_s whose starts gsegS[b] are monotone in b (global
// scan is bin-major, chunk-minor -- correct for the tail chunk too).
// Phase 1: gather runs into 8KB LDS lbuf (~512 line-touches vs 2048 random).
// Phase 2: bin = binary-search(inv[i] in gsegS) -> last start <= g, which is
// the non-empty containing run even with empty-run ties; dense out writes.
__global__ __launch_bounds__(256) void unscatter_kernel(
    const float* __restrict__ val_s, const unsigned* __restrict__ inv,
    const unsigned* __restrict__ seg, const unsigned* __restrict__ stot,
    int nstripe, float* __restrict__ out, int n, int nblk)
{
    __shared__ unsigned sc[256], soff[256];       // 2 KB
    __shared__ unsigned gsegS[NB];                // 2 KB (monotone run starts)
    __shared__ unsigned lrs[NB];                  // 2 KB (local run starts)
    __shared__ float lbuf[CHUNK];                 // 8 KB

    local_stripe_scan(stot, nstripe, soff, sc);

    int blk = chunk_swizzle(blockIdx.x, nblk);    // same mapping as partition
    int tid = threadIdx.x;
    int c0 = blk * CHUNK;

    // this chunk's 512 run starts (global) + lengths
    unsigned len2[2];
#pragma unroll
    for (int j = 0; j < 2; ++j) {
        int b = 2 * tid + j;
        int idx = b * nblk + blk;
        unsigned st = seg[idx] + soff[idx >> 13];
        gsegS[b] = st;
        int idx1 = idx + 1;
        unsigned en = (idx1 < NB * nblk) ? (seg[idx1] + soff[idx1 >> 13])
                                         : (unsigned)n;
        len2[j] = en - st;
    }
    sc[tid] = len2[0] + len2[1];
    __syncthreads();                               // covers gsegS + sc
    for (int off = 1; off < 256; off <<= 1) {
        unsigned v = (tid >= off) ? sc[tid - off] : 0u;
        __syncthreads();
        sc[tid] += v;
        __syncthreads();
    }
    unsigned base = (tid == 0) ? 0u : sc[tid - 1];
    lrs[2 * tid] = base;
    lrs[2 * tid + 1] = base + len2[0];
    __syncthreads();

    // phase 1: gather this chunk's values (bin-major) into lbuf
#pragma unroll
    for (int j = 0; j < 2; ++j) {
        int b = 2 * tid + j;
        unsigned st = gsegS[b], l = len2[j], d = lrs[b];
        for (unsigned k = 0; k < l; ++k) lbuf[d + k] = val_s[st + k];
    }
    __syncthreads();

    // phase 2: dense writes via 9-step binary search in monotone gsegS
#pragma unroll
    for (int k = 0; k < KPT; ++k) {
        int i = c0 + tid + k * 256;
        if (i < n) {
            unsigned g = inv[i];
            unsigned lo = 0, hi = NB;
            while (hi - lo > 1) {
                unsigned mid = (lo + hi) >> 1;
                if (gsegS[mid] <= g) lo = mid; else hi = mid;
            }
            out[i] = lbuf[lrs[lo] + (g - gsegS[lo])];
        }
    }
}

// Fallback (round-1 proven) if ws/config insufficient.
__global__ __launch_bounds__(256) void eval_unsorted_kernel(
    const float* __restrict__ pts, const float* __restrict__ cp,
    float* __restrict__ out, int n)
{
    int i = blockIdx.x * blockDim.x + threadIdx.x;
    if (i >= n) return;
    float tx, ty, tz; bool inb;
    load_pt(pts, i, tx, ty, tz, inb);
    int ix = (int)tx, iy = (int)ty, iz = (int)tz;
    float wx[4], wy[4], wz[4];
    bspline_w(tx - (float)ix, wx);
    bspline_w(ty - (float)iy, wy);
    bspline_w(tz - (float)iz, wz);
    const float* bse = cp + (size_t)(ix - 1) * SLAB + (size_t)(iy - 1) * GRID_DIM + (iz - 1);
    float acc = 0.0f;
#pragma unroll
    for (int a = 0; a < 4; ++a) {
        float accy = 0.0f;
#pragma unroll
        for (int b = 0; b < 4; ++b) {
            const float* row = bse + a * SLAB + b * GRID_DIM;
            float4 v;
            __builtin_memcpy(&v, row, 16);
            float sz = fmaf(v.x, wz[0], fmaf(v.y, wz[1], fmaf(v.z, wz[2], v.w * wz[3])));
            accy = fmaf(wy[b], sz, accy);
        }
        acc = fmaf(wx[a], accy, acc);
    }
    out[i] = inb ? acc : 0.0f;
}

extern "C" void kernel_launch(void* const* d_in, const int* in_sizes, int n_in,
                              void* d_out, int out_size, void* d_ws, size_t ws_size,
                              hipStream_t stream) {
    const float* pts = (const float*)d_in[0];      // (N, 3) fp32
    const float* cp  = (const float*)d_in[1];      // (1, 132, 132, 132) fp32
    float* out       = (float*)d_out;              // (N, 1) fp32

    int n = in_sizes[0] / 3;                       // 2,000,000
    int nblk = (n + CHUNK - 1) / CHUNK;            // 977
    int TOT = NB * nblk;                           // 500,224
    int nstripe = (TOT + STRIPE - 1) / STRIPE;     // 62

    // ws layout (all fully rewritten every call; no memsets needed):
    // bh[TOT] | seg[TOT] | stot[256] | sorted f4[n] | inv u32[n] | val_s f32[n]
    size_t A          = (((size_t)TOT * 4) + 1023) & ~(size_t)1023;
    size_t off_seg    = A;
    size_t off_stot   = 2 * A;
    size_t off_sorted = 2 * A + 1024;
    size_t off_inv    = off_sorted + (size_t)n * sizeof(float4);
    size_t off_val    = off_inv    + (size_t)n * sizeof(unsigned);
    size_t need       = off_val    + (size_t)n * sizeof(float);

    if (ws_size >= need && nblk <= 1024 && nstripe <= 256) {
        unsigned* bh     = (unsigned*)d_ws;
        unsigned* seg    = (unsigned*)((char*)d_ws + off_seg);
        unsigned* stot   = (unsigned*)((char*)d_ws + off_stot);
        float4*   sorted = (float4*)((char*)d_ws + off_sorted);
        unsigned* inv    = (unsigned*)((char*)d_ws + off_inv);
        float*    val_s  = (float*)((char*)d_ws + off_val);

        hipLaunchKernelGGL(hist512_kernel, dim3(nblk), dim3(256), 0, stream,
                           pts, n, nblk, bh);
        hipLaunchKernelGGL(scan_l1_kernel, dim3(nstripe), dim3(256), 0, stream,
                           bh, seg, stot, TOT);
        hipLaunchKernelGGL(partition_kernel, dim3(nblk), dim3(256), 0, stream,
                           pts, n, nblk, seg, stot, nstripe, sorted, inv);
        hipLaunchKernelGGL(eval_kernel, dim3(NB), dim3(512), 0, stream,
                           sorted, cp, seg, stot, nstripe, val_s, n, nblk);
        hipLaunchKernelGGL(unscatter_kernel, dim3(nblk), dim3(256), 0, stream,
                           val_s, inv, seg, stot, nstripe, out, n, nblk);
    } else {
        hipLaunchKernelGGL(eval_unsorted_kernel, dim3((n + 255) / 256), dim3(256), 0, stream,
                           pts, cp, out, n);
    }
}

// Round 11
// 149.590 us; speedup vs baseline: 2.5666x; 1.1778x over previous
//
#include <hip/hip_runtime.h>

#define GRID_DIM 132
#define SLAB (GRID_DIM * GRID_DIM)   // 17424
#define NB 512                       // 8x8x8 bins, each 16^3 in int(t) space
#define CHUNK 4096                   // points per partition/hist block
#define KPT (CHUNK / 256)            // 16 points per thread
#define REG 20                       // staged region edge (max tap index 19)
#define REG2 (REG * REG)
#define REG3 (REG * REG * REG)       // 8000 floats = 32 KB
#define STRIPE 8192                  // entries per scan_l1 block (2^13)

__device__ __forceinline__ void bspline_w(float x, float w[4]) {
    float omx = 1.0f - x;
    w[0] = omx * omx * omx * (1.0f / 6.0f);
    w[1] = (3.0f * (x - 2.0f) * x * x + 4.0f) * (1.0f / 6.0f);
    w[2] = (-3.0f * omx * omx * (x + 1.0f) + 4.0f) * (1.0f / 6.0f);
    w[3] = x * x * x * (1.0f / 6.0f);
}

__device__ __forceinline__ void load_pt(const float* __restrict__ pts, int i,
                                        float& tx, float& ty, float& tz, bool& inb) {
    tx = pts[3 * i + 0] + 1.0f;   // ORIGIN = -(1+1e-8) == -1.0f in fp32, STEP = 1
    ty = pts[3 * i + 1] + 1.0f;
    tz = pts[3 * i + 2] + 1.0f;
    inb = (tx >= 1.0f) && (ty >= 1.0f) && (tz >= 1.0f) &&
          (tx < 130.0f) && (ty < 130.0f) && (tz < 130.0f);
    if (!inb) { tx = ty = tz = 1.0f; }
}

// 512-bin id, x-major (proven)
__device__ __forceinline__ int calc_bin(float tx, float ty, float tz) {
    int bx = min(7, ((int)tx - 1) >> 4);
    int by = min(7, ((int)ty - 1) >> 4);
    int bz = min(7, ((int)tz - 1) >> 4);
    return (bx << 6) | (by << 3) | bz;
}

// m204 bijective XCD swizzle over chunk ids (adjacent chunks -> same XCD so
// their adjacent 64-128B runs assemble into full lines in that L2).
__device__ __forceinline__ int chunk_swizzle(int bid, int nblk) {
    int q = nblk >> 3, r = nblk & 7;
    int xcd = bid & 7, pos = bid >> 3;
    return (xcd < r ? xcd * (q + 1) : r * (q + 1) + (xcd - r) * q) + pos;
}

// In-LDS exclusive scan of stripe totals (<=256). Barriers unconditional.
__device__ __forceinline__ void local_stripe_scan(
    const unsigned* __restrict__ stot, int nstripe,
    unsigned* soff, unsigned* sc)
{
    int t = threadIdx.x;
    if (t < 256) sc[t] = (t < nstripe) ? stot[t] : 0u;
    __syncthreads();
    for (int off = 1; off < 256; off <<= 1) {
        unsigned v = (t >= off && t < 256) ? sc[t - off] : 0u;
        __syncthreads();
        if (t < 256) sc[t] += v;
        __syncthreads();
    }
    if (t < 256) soff[t] = (t == 0) ? 0u : sc[t - 1];
    __syncthreads();
}

// Per-chunk 512-bin histogram -> bh[bin*nblk + blk] (bin-major). No global atomics.
__global__ __launch_bounds__(256) void hist512_kernel(
    const float* __restrict__ pts, int n, int nblk, unsigned* __restrict__ bh)
{
    __shared__ unsigned lh[NB];
    int tid = threadIdx.x, blk = blockIdx.x;
    int c0 = blk * CHUNK;
    for (int b = tid; b < NB; b += 256) lh[b] = 0u;
    __syncthreads();
#pragma unroll
    for (int k = 0; k < KPT; ++k) {
        int i = c0 + tid + k * 256;
        if (i < n) {
            float tx, ty, tz; bool inb;
            load_pt(pts, i, tx, ty, tz, inb);
            atomicAdd(&lh[calc_bin(tx, ty, tz)], 1u);
        }
    }
    __syncthreads();
    for (int b = tid; b < NB; b += 256) bh[b * nblk + blk] = lh[b];
}

// Stripe-local exclusive scan (8192 entries/block) + stripe totals.
__global__ __launch_bounds__(256) void scan_l1_kernel(
    const unsigned* __restrict__ bh, unsigned* __restrict__ seg,
    unsigned* __restrict__ stot, int TOT)
{
    __shared__ unsigned sc[256];
    int t = threadIdx.x;
    int base_idx = blockIdx.x * STRIPE + t * 32;
    unsigned local[32];
    unsigned s = 0;
#pragma unroll
    for (int j = 0; j < 32; ++j) {
        int idx = base_idx + j;
        unsigned v = (idx < TOT) ? bh[idx] : 0u;
        local[j] = v; s += v;
    }
    sc[t] = s;
    __syncthreads();
    for (int off = 1; off < 256; off <<= 1) {
        unsigned v = (t >= off) ? sc[t - off] : 0u;
        __syncthreads();
        sc[t] += v;
        __syncthreads();
    }
    unsigned run = (t == 0) ? 0u : sc[t - 1];
#pragma unroll
    for (int j = 0; j < 32; ++j) {
        int idx = base_idx + j;
        if (idx < TOT) seg[idx] = run;
        run += local[j];
    }
    if (t == 255) stot[blockIdx.x] = sc[255];
}

// Bufless partition (proven r8, minus the inv write): LDS cursors seeded with
// deterministic global segment starts; one pass, direct register->global
// writes into per-(chunk,bin) runs (avg 128B with CHUNK=4096).
__global__ __launch_bounds__(256) void partition_kernel(
    const float* __restrict__ pts, int n, int nblk,
    const unsigned* __restrict__ seg, const unsigned* __restrict__ stot,
    int nstripe, float4* __restrict__ sorted)
{
    __shared__ unsigned lcur[NB];                 // 2 KB
    __shared__ unsigned sc[256], soff[256];       // 2 KB

    local_stripe_scan(stot, nstripe, soff, sc);

    int blk = chunk_swizzle(blockIdx.x, nblk);
    int tid = threadIdx.x;
    int c0 = blk * CHUNK;

    for (int b = tid; b < NB; b += 256) {
        int idx = b * nblk + blk;
        lcur[b] = seg[idx] + soff[idx >> 13];     // STRIPE = 2^13
    }
    __syncthreads();

#pragma unroll
    for (int k = 0; k < KPT; ++k) {
        int i = c0 + tid + k * 256;
        if (i < n) {
            float tx, ty, tz; bool inb;
            load_pt(pts, i, tx, ty, tz, inb);
            int bin = calc_bin(tx, ty, tz);
            unsigned g = atomicAdd(&lcur[bin], 1u);
            unsigned tag = (unsigned)i | (inb ? 0u : 0x80000000u);
            sorted[g] = make_float4(tx, ty, tz, __uint_as_float(tag));
        }
    }
}

// One 512-thread block per bin: stage the bin's 20^3 region in LDS ONCE,
// evaluate its points (taps hit 32 LDS banks in parallel), write out[orig]
// DIRECTLY (random 4B stores into the 8MB L3-resident output -- assembled in
// L2/L3; replaces the whole inv/val_s/unscatter pass). (eval math proven r7-r10.)
__global__ __launch_bounds__(512) void eval_kernel(
    const float4* __restrict__ sorted, const float* __restrict__ cp,
    const unsigned* __restrict__ seg, const unsigned* __restrict__ stot,
    int nstripe, float* __restrict__ out, int n, int nblk)
{
    __shared__ float region[REG3];   // 32 KB
    __shared__ unsigned sc[256], soff[256];

    local_stripe_scan(stot, nstripe, soff, sc);

    int bid = blockIdx.x;
    int bin = (bid & 7) * 64 + (bid >> 3);   // 512 = 8 XCDs x 64 bins
    int x0 = (bin >> 6) << 4, y0 = ((bin >> 3) & 7) << 4, z0 = (bin & 7) << 4;

    const float* src = cp + (size_t)x0 * SLAB + y0 * GRID_DIM + z0;
    for (int v = threadIdx.x; v < REG3; v += 512) {
        int gx = v / REG2;
        int rr = v - gx * REG2;
        int gy = rr / REG;
        int gz = rr - gy * REG;
        region[v] = src[gx * SLAB + gy * GRID_DIM + gz];
    }
    __syncthreads();

    int i0 = bin * nblk;
    unsigned s = seg[i0] + soff[i0 >> 13];
    unsigned e;
    if (bin == NB - 1) e = (unsigned)n;
    else { int i1 = (bin + 1) * nblk; e = seg[i1] + soff[i1 >> 13]; }

    for (unsigned i = s + threadIdx.x; i < e; i += 512) {
        float4 p = sorted[i];
        unsigned tag = __float_as_uint(p.w);
        int ix = (int)p.x, iy = (int)p.y, iz = (int)p.z;
        float wx[4], wy[4], wz[4];
        bspline_w(p.x - (float)ix, wx);
        bspline_w(p.y - (float)iy, wy);
        bspline_w(p.z - (float)iz, wz);
        int lx = ix - 1 - x0, ly = iy - 1 - y0, lz = iz - 1 - z0;
        const float* rb = region + (lx * REG + ly) * REG + lz;
        float acc = 0.0f;
#pragma unroll
        for (int a = 0; a < 4; ++a) {
            float accy = 0.0f;
#pragma unroll
            for (int b = 0; b < 4; ++b) {
                const float* row = rb + (a * REG + b) * REG;
                float sz = fmaf(row[0], wz[0], fmaf(row[1], wz[1],
                           fmaf(row[2], wz[2], row[3] * wz[3])));
                accy = fmaf(wy[b], sz, accy);
            }
            acc = fmaf(wx[a], accy, acc);
        }
        int orig = (int)(tag & 0x7fffffffu);
        out[orig] = (tag >> 31) ? 0.0f : acc;   // each orig written exactly once
    }
}

// Fallback (round-1 proven) if ws/config insufficient.
__global__ __launch_bounds__(256) void eval_unsorted_kernel(
    const float* __restrict__ pts, const float* __restrict__ cp,
    float* __restrict__ out, int n)
{
    int i = blockIdx.x * blockDim.x + threadIdx.x;
    if (i >= n) return;
    float tx, ty, tz; bool inb;
    load_pt(pts, i, tx, ty, tz, inb);
    int ix = (int)tx, iy = (int)ty, iz = (int)tz;
    float wx[4], wy[4], wz[4];
    bspline_w(tx - (float)ix, wx);
    bspline_w(ty - (float)iy, wy);
    bspline_w(tz - (float)iz, wz);
    const float* bse = cp + (size_t)(ix - 1) * SLAB + (size_t)(iy - 1) * GRID_DIM + (iz - 1);
    float acc = 0.0f;
#pragma unroll
    for (int a = 0; a < 4; ++a) {
        float accy = 0.0f;
#pragma unroll
        for (int b = 0; b < 4; ++b) {
            const float* row = bse + a * SLAB + b * GRID_DIM;
            float4 v;
            __builtin_memcpy(&v, row, 16);
            float sz = fmaf(v.x, wz[0], fmaf(v.y, wz[1], fmaf(v.z, wz[2], v.w * wz[3])));
            accy = fmaf(wy[b], sz, accy);
        }
        acc = fmaf(wx[a], accy, acc);
    }
    out[i] = inb ? acc : 0.0f;
}

extern "C" void kernel_launch(void* const* d_in, const int* in_sizes, int n_in,
                              void* d_out, int out_size, void* d_ws, size_t ws_size,
                              hipStream_t stream) {
    const float* pts = (const float*)d_in[0];      // (N, 3) fp32
    const float* cp  = (const float*)d_in[1];      // (1, 132, 132, 132) fp32
    float* out       = (float*)d_out;              // (N, 1) fp32

    int n = in_sizes[0] / 3;                       // 2,000,000
    int nblk = (n + CHUNK - 1) / CHUNK;            // 489
    int TOT = NB * nblk;                           // 250,368
    int nstripe = (TOT + STRIPE - 1) / STRIPE;     // 31

    // ws layout (all fully rewritten every call; no memsets needed):
    // bh[TOT] | seg[TOT] | stot[256] | sorted f4[n]
    size_t A          = (((size_t)TOT * 4) + 1023) & ~(size_t)1023;
    size_t off_seg    = A;
    size_t off_stot   = 2 * A;
    size_t off_sorted = 2 * A + 1024;
    size_t need       = off_sorted + (size_t)n * sizeof(float4);

    if (ws_size >= need && nblk <= 1024 && nstripe <= 256) {
        unsigned* bh     = (unsigned*)d_ws;
        unsigned* seg    = (unsigned*)((char*)d_ws + off_seg);
        unsigned* stot   = (unsigned*)((char*)d_ws + off_stot);
        float4*   sorted = (float4*)((char*)d_ws + off_sorted);

        hipLaunchKernelGGL(hist512_kernel, dim3(nblk), dim3(256), 0, stream,
                           pts, n, nblk, bh);
        hipLaunchKernelGGL(scan_l1_kernel, dim3(nstripe), dim3(256), 0, stream,
                           bh, seg, stot, TOT);
        hipLaunchKernelGGL(partition_kernel, dim3(nblk), dim3(256), 0, stream,
                           pts, n, nblk, seg, stot, nstripe, sorted);
        hipLaunchKernelGGL(eval_kernel, dim3(NB), dim3(512), 0, stream,
                           sorted, cp, seg, stot, nstripe, out, n, nblk);
    } else {
        hipLaunchKernelGGL(eval_unsorted_kernel, dim3((n + 255) / 256), dim3(256), 0, stream,
                           pts, cp, out, n);
    }
}